// Round 1
// baseline (743.593 us; speedup 1.0000x reference)
//
#include <hip/hip_runtime.h>

// Problem dims (hardcoded from reference)
#define T_STEPS 100
#define B_N     128
#define IN_F    512
#define OUT_F   512

// fp64 decay constants: exp(-DT/TAU_*)
#define ALPHA_D 0.8187307530779818   // exp(-1/5)   synaptic
#define BETA_D  0.9512294245007140   // exp(-1/20)  membrane
// gamma (trace) == beta since TAU_TRACE == TAU_MEM == 20

// ---------------------------------------------------------------------------
// K1: transpose W (OUT x IN) -> Wt (IN x OUT) so that gathering column i of
// W.T is a coalesced row read across consecutive output lanes.
// ---------------------------------------------------------------------------
__global__ __launch_bounds__(256) void transposeW(const float* __restrict__ W,
                                                  float* __restrict__ Wt) {
    __shared__ float tile[32][33];
    const int bx = blockIdx.x & 15;   // i-tile
    const int by = blockIdx.x >> 4;   // o-tile
    const int tx = threadIdx.x & 31;
    const int ty = threadIdx.x >> 5;  // 0..7
#pragma unroll
    for (int k = 0; k < 32; k += 8) {
        int o = by * 32 + ty + k;
        tile[ty + k][tx] = W[o * IN_F + bx * 32 + tx];
    }
    __syncthreads();
#pragma unroll
    for (int k = 0; k < 32; k += 8) {
        int i = bx * 32 + ty + k;
        Wt[i * OUT_F + by * 32 + tx] = tile[tx][ty + k];
    }
}

// ---------------------------------------------------------------------------
// K2: LIF scan. One wave (64 threads) per (b, o-chunk of 64). 1024 blocks.
// Per time step: wave cooperatively ballots the 512 input spikes into 8
// 64-bit masks (in registers), then each lane walks the set bits and
// accumulates W.T columns in fp64. I/U recurrence carried in fp64 so the
// spike decisions match a float64 numpy reference bit-for-bit in practice.
// Block order: blockIdx = chunk*128 + b  =>  blockIdx % 8 == b % 8, so all 8
// o-chunks of a batch land on the same XCD (L2 reuse of x rows).
// ---------------------------------------------------------------------------
__global__ __launch_bounds__(64) void lif_scan(const float* __restrict__ x,
                                               const float* __restrict__ Wt,
                                               float* __restrict__ S_out,
                                               float* __restrict__ Uh) {
    const int lane  = threadIdx.x;          // 0..63
    const int b     = blockIdx.x & (B_N - 1);
    const int chunk = blockIdx.x >> 7;      // 0..7
    const int o     = chunk * 64 + lane;

    const float* Wtc = Wt + o;              // Wt[i*OUT_F + o]
    double I = 0.0, U = 0.0;

    // prefetch t=0 spikes
    float v[8];
    {
        const float* xr = x + (size_t)b * IN_F;
#pragma unroll
        for (int j = 0; j < 8; ++j) v[j] = xr[j * 64 + lane];
    }

    for (int t = 0; t < T_STEPS; ++t) {
        unsigned long long m[8];
#pragma unroll
        for (int j = 0; j < 8; ++j) m[j] = __ballot(v[j] > 0.5f);

        // prefetch next step's spikes (independent of this step's compute)
        if (t + 1 < T_STEPS) {
            const float* xn = x + (size_t)(t + 1) * (B_N * IN_F) + (size_t)b * IN_F;
#pragma unroll
            for (int j = 0; j < 8; ++j) v[j] = xn[j * 64 + lane];
        }

        // sparse synaptic sum: sum over active i of Wt[i][o], fp64
        double s0 = 0.0, s1 = 0.0;
#pragma unroll
        for (int j = 0; j < 8; ++j) {
            unsigned long long mm = m[j];
            const float* wb = Wtc + (size_t)(j * 64) * OUT_F;
            double acc = 0.0;
            while (mm) {
                int k = __builtin_ctzll(mm);
                mm &= mm - 1;
                acc += (double)wb[(size_t)k * OUT_F];
            }
            if (j & 1) s1 += acc; else s0 += acc;
        }

        I = ALPHA_D * I + (s0 + s1);
        U = BETA_D * U + I;
        const double Sv = (U >= 1.0) ? 1.0 : 0.0;

        const size_t base = (size_t)t * (B_N * OUT_F) + (size_t)b * OUT_F + o;
        S_out[base] = (float)Sv;
        Uh[(size_t)(2 * t) * (B_N * OUT_F) + (size_t)b * OUT_F + o] = (float)U;   // U_pre
        U -= Sv;                                                                  // first reset
        Uh[(size_t)(2 * t + 1) * (B_N * OUT_F) + (size_t)b * OUT_F + o] = (float)U; // U_post
        U -= Sv;                                                                  // second reset (as in source)
    }
}

// ---------------------------------------------------------------------------
// K3: trace[b,o,i] = sum_t gamma^(T-1-t) * sigma'(U_post[t,b,o]) * x[t,b,i]
// Batched GEMM, 64x64 output tile per block, K = T_STEPS = 100.
// sigma' * gamma^k is recomputed from U_post (already in d_out) during LDS
// staging -> no intermediate buffer beyond Wt in ws.
// blockIdx = tile*128 + b  =>  all tiles of a batch on one XCD.
// ---------------------------------------------------------------------------
__global__ __launch_bounds__(256) void trace_gemm(const float* __restrict__ x,
                                                  const float* __restrict__ Uh,
                                                  float* __restrict__ trace) {
    __shared__ float Pl[T_STEPS][64];
    __shared__ float Xl[T_STEPS][64];

    const int b    = blockIdx.x & (B_N - 1);
    const int tile = blockIdx.x >> 7;     // 0..63
    const int ot   = tile >> 3;           // o-tile 0..7
    const int it   = tile & 7;            // i-tile 0..7
    const int tid  = threadIdx.x;

    // stage P (sigma' * gamma^(T-1-t)) and X tiles: 6400 elements each
#pragma unroll 1
    for (int idx = tid; idx < T_STEPS * 64; idx += 256) {
        const int t   = idx >> 6;
        const int col = idx & 63;
        // U_post lives at U_hist[2t+1]
        float u  = Uh[(size_t)(2 * t + 1) * (B_N * OUT_F) + (size_t)b * OUT_F + ot * 64 + col];
        float du = fabsf(u - 1.0f);
        float d  = 1.0f + 0.03f * du;
        float sp = 1.0f / (d * d);
        float gp = __expf(-0.05f * (float)(T_STEPS - 1 - t));  // gamma^(T-1-t)
        Pl[t][col] = sp * gp;
        Xl[t][col] = x[(size_t)t * (B_N * IN_F) + (size_t)b * IN_F + it * 64 + col];
    }
    __syncthreads();

    const int to = tid >> 4;   // 0..15 -> o sub-row *4
    const int ti = tid & 15;   // 0..15 -> i sub-col *4
    float4 acc0 = {0, 0, 0, 0}, acc1 = {0, 0, 0, 0}, acc2 = {0, 0, 0, 0}, acc3 = {0, 0, 0, 0};

#pragma unroll 4
    for (int t = 0; t < T_STEPS; ++t) {
        const float4 po = *(const float4*)&Pl[t][to * 4];
        const float4 xi = *(const float4*)&Xl[t][ti * 4];
        acc0.x += po.x * xi.x; acc0.y += po.x * xi.y; acc0.z += po.x * xi.z; acc0.w += po.x * xi.w;
        acc1.x += po.y * xi.x; acc1.y += po.y * xi.y; acc1.z += po.y * xi.z; acc1.w += po.y * xi.w;
        acc2.x += po.z * xi.x; acc2.y += po.z * xi.y; acc2.z += po.z * xi.z; acc2.w += po.z * xi.w;
        acc3.x += po.w * xi.x; acc3.y += po.w * xi.y; acc3.z += po.w * xi.z; acc3.w += po.w * xi.w;
    }

    float* tb = trace + (size_t)b * (OUT_F * IN_F) + (size_t)(ot * 64 + to * 4) * IN_F + it * 64 + ti * 4;
    *(float4*)(tb + 0 * IN_F) = acc0;
    *(float4*)(tb + 1 * IN_F) = acc1;
    *(float4*)(tb + 2 * IN_F) = acc2;
    *(float4*)(tb + 3 * IN_F) = acc3;
}

// ---------------------------------------------------------------------------
extern "C" void kernel_launch(void* const* d_in, const int* in_sizes, int n_in,
                              void* d_out, int out_size, void* d_ws, size_t ws_size,
                              hipStream_t stream) {
    const float* x = (const float*)d_in[0];   // (T, B, IN) binary spikes
    const float* W = (const float*)d_in[1];   // (OUT, IN)

    float* out   = (float*)d_out;
    float* S_out = out;                                            // (T, B, OUT)
    float* Uh    = out + (size_t)T_STEPS * B_N * OUT_F;            // (2T, B, OUT)
    float* trace = Uh + (size_t)2 * T_STEPS * B_N * OUT_F;         // (B, OUT, IN)

    float* Wt = (float*)d_ws;                                      // (IN, OUT), 1 MiB

    transposeW<<<256, 256, 0, stream>>>(W, Wt);
    lif_scan<<<1024, 64, 0, stream>>>(x, Wt, S_out, Uh);
    trace_gemm<<<64 * B_N, 256, 0, stream>>>(x, Uh, trace);
}

// Round 2
// 226.193 us; speedup vs baseline: 3.2874x; 3.2874x over previous
//
#include <hip/hip_runtime.h>

// Problem dims (hardcoded from reference)
#define T_STEPS 100
#define B_N     128
#define IN_F    512
#define OUT_F   512

// fp64 decay constants: exp(-DT/TAU_*)
#define ALPHA_D 0.8187307530779818   // exp(-1/5)   synaptic
#define BETA_D  0.9512294245007140   // exp(-1/20)  membrane

// ---------------------------------------------------------------------------
// K1: transpose W (OUT x IN) -> Wt (IN x OUT): gathering row i of Wt is a
// coalesced read across consecutive output lanes.
// ---------------------------------------------------------------------------
__global__ __launch_bounds__(256) void transposeW(const float* __restrict__ W,
                                                  float* __restrict__ Wt) {
    __shared__ float tile[32][33];
    const int bx = blockIdx.x & 15;   // i-tile
    const int by = blockIdx.x >> 4;   // o-tile
    const int tx = threadIdx.x & 31;
    const int ty = threadIdx.x >> 5;  // 0..7
#pragma unroll
    for (int k = 0; k < 32; k += 8) {
        int o = by * 32 + ty + k;
        tile[ty + k][tx] = W[o * IN_F + bx * 32 + tx];
    }
    __syncthreads();
#pragma unroll
    for (int k = 0; k < 32; k += 8) {
        int i = bx * 32 + ty + k;
        Wt[i * OUT_F + by * 32 + tx] = tile[tx][ty + k];
    }
}

// ---------------------------------------------------------------------------
// K_A: C[t,b,o] = sum over active i of Wt[i][o], fp64. One block per (t,b),
// fully parallel over 12800 blocks -> latency hidden by TLP (unlike the old
// serial-scan bit-walk). Wave 0 builds a DETERMINISTIC ascending active-index
// list via ballot + popcount prefix; then all 256 threads run a uniform loop
// of coalesced Wt-row loads (Wt = 1 MB, L2-resident on every XCD).
// ---------------------------------------------------------------------------
__global__ __launch_bounds__(256) void syn_current(const float* __restrict__ x,
                                                   const float* __restrict__ Wt,
                                                   double* __restrict__ C) {
    const int tb  = blockIdx.x;          // t*B + b : exactly the x row index
    const int tid = threadIdx.x;

    __shared__ int s_idx[IN_F];
    __shared__ int s_cnt;

    if (tid < 64) {                      // wave 0 only
        const float* xr = x + (size_t)tb * IN_F;
        int base = 0;
#pragma unroll
        for (int j = 0; j < 8; ++j) {
            const float v = xr[j * 64 + tid];
            const unsigned long long m = __ballot(v > 0.5f);
            if (v > 0.5f) {
                const int pos = base + __popcll(m & ((1ull << tid) - 1ull));
                s_idx[pos] = j * 64 + tid;
            }
            base += __popcll(m);
        }
        if (tid == 0) s_cnt = base;
    }
    __syncthreads();

    const int cnt = s_cnt;
    double c0 = 0.0, c1 = 0.0;
    const float* W0 = Wt + tid;
    const float* W1 = Wt + tid + 256;
    for (int k = 0; k < cnt; ++k) {
        const int i = s_idx[k];          // LDS broadcast (uniform address)
        c0 += (double)W0[(size_t)i * OUT_F];
        c1 += (double)W1[(size_t)i * OUT_F];
    }

    double* Cr = C + (size_t)tb * OUT_F;
    Cr[tid]       = c0;
    Cr[tid + 256] = c1;
}

// ---------------------------------------------------------------------------
// K_B: elementwise LIF scan, one thread per (b,o). fp64 recurrence; C loads
// are independent -> double-buffered 10-step chunks (named bufA/bufB so all
// register-array indices are compile-time constants; no scratch spill).
// ---------------------------------------------------------------------------
#define LIF_STEP(BUF, J, CB)                                                   \
    {                                                                          \
        const int t = (CB) * 10 + (J);                                         \
        I = ALPHA_D * I + BUF[J];                                              \
        U = BETA_D * U + I;                                                    \
        const double Sv = (U >= 1.0) ? 1.0 : 0.0;                              \
        S_out[(size_t)t * N + pos] = (float)Sv;                                \
        Uh[(size_t)(2 * t) * N + pos] = (float)U;                              \
        U -= Sv;                                                               \
        Uh[(size_t)(2 * t + 1) * N + pos] = (float)U;                          \
        U -= Sv;                                                               \
    }

__global__ __launch_bounds__(256) void lif_pointwise(const double* __restrict__ C,
                                                     float* __restrict__ S_out,
                                                     float* __restrict__ Uh) {
    const int pos = blockIdx.x * 256 + threadIdx.x;   // b*OUT + o
    const size_t N = (size_t)B_N * OUT_F;

    double I = 0.0, U = 0.0;
    double bufA[10], bufB[10];

#pragma unroll
    for (int j = 0; j < 10; ++j) bufA[j] = C[(size_t)j * N + pos];

    for (int cb = 0; cb < 10; cb += 2) {
        // prefetch chunk cb+1 into bufB (always exists: cb<=8 -> cb+1<=9)
#pragma unroll
        for (int j = 0; j < 10; ++j) bufB[j] = C[((size_t)(cb + 1) * 10 + j) * N + pos];
#pragma unroll
        for (int j = 0; j < 10; ++j) LIF_STEP(bufA, j, cb)
        // prefetch chunk cb+2 into bufA
        if (cb + 2 < 10) {
#pragma unroll
            for (int j = 0; j < 10; ++j) bufA[j] = C[((size_t)(cb + 2) * 10 + j) * N + pos];
        }
#pragma unroll
        for (int j = 0; j < 10; ++j) LIF_STEP(bufB, j, cb + 1)
    }
}

// ---------------------------------------------------------------------------
// K3: trace[b,o,i] = sum_t gamma^(T-1-t) * sigma'(U_post[t,b,o]) * x[t,b,i]
// Batched GEMM, 64x64 output tile per block, K = 100. (unchanged)
// ---------------------------------------------------------------------------
__global__ __launch_bounds__(256) void trace_gemm(const float* __restrict__ x,
                                                  const float* __restrict__ Uh,
                                                  float* __restrict__ trace) {
    __shared__ float Pl[T_STEPS][64];
    __shared__ float Xl[T_STEPS][64];

    const int b    = blockIdx.x & (B_N - 1);
    const int tile = blockIdx.x >> 7;     // 0..63
    const int ot   = tile >> 3;           // o-tile 0..7
    const int it   = tile & 7;            // i-tile 0..7
    const int tid  = threadIdx.x;

#pragma unroll 1
    for (int idx = tid; idx < T_STEPS * 64; idx += 256) {
        const int t   = idx >> 6;
        const int col = idx & 63;
        float u  = Uh[(size_t)(2 * t + 1) * (B_N * OUT_F) + (size_t)b * OUT_F + ot * 64 + col];
        float du = fabsf(u - 1.0f);
        float d  = 1.0f + 0.03f * du;
        float sp = 1.0f / (d * d);
        float gp = __expf(-0.05f * (float)(T_STEPS - 1 - t));  // gamma^(T-1-t)
        Pl[t][col] = sp * gp;
        Xl[t][col] = x[(size_t)t * (B_N * IN_F) + (size_t)b * IN_F + it * 64 + col];
    }
    __syncthreads();

    const int to = tid >> 4;
    const int ti = tid & 15;
    float4 acc0 = {0, 0, 0, 0}, acc1 = {0, 0, 0, 0}, acc2 = {0, 0, 0, 0}, acc3 = {0, 0, 0, 0};

#pragma unroll 4
    for (int t = 0; t < T_STEPS; ++t) {
        const float4 po = *(const float4*)&Pl[t][to * 4];
        const float4 xi = *(const float4*)&Xl[t][ti * 4];
        acc0.x += po.x * xi.x; acc0.y += po.x * xi.y; acc0.z += po.x * xi.z; acc0.w += po.x * xi.w;
        acc1.x += po.y * xi.x; acc1.y += po.y * xi.y; acc1.z += po.y * xi.z; acc1.w += po.y * xi.w;
        acc2.x += po.z * xi.x; acc2.y += po.z * xi.y; acc2.z += po.z * xi.z; acc2.w += po.z * xi.w;
        acc3.x += po.w * xi.x; acc3.y += po.w * xi.y; acc3.z += po.w * xi.z; acc3.w += po.w * xi.w;
    }

    float* tb = trace + (size_t)b * (OUT_F * IN_F) + (size_t)(ot * 64 + to * 4) * IN_F + it * 64 + ti * 4;
    *(float4*)(tb + 0 * IN_F) = acc0;
    *(float4*)(tb + 1 * IN_F) = acc1;
    *(float4*)(tb + 2 * IN_F) = acc2;
    *(float4*)(tb + 3 * IN_F) = acc3;
}

// ---------------------------------------------------------------------------
extern "C" void kernel_launch(void* const* d_in, const int* in_sizes, int n_in,
                              void* d_out, int out_size, void* d_ws, size_t ws_size,
                              hipStream_t stream) {
    const float* x = (const float*)d_in[0];   // (T, B, IN) binary spikes
    const float* W = (const float*)d_in[1];   // (OUT, IN)

    float* out   = (float*)d_out;
    float* S_out = out;                                            // (T, B, OUT)
    float* Uh    = out + (size_t)T_STEPS * B_N * OUT_F;            // (2T, B, OUT)
    float* trace = Uh + (size_t)2 * T_STEPS * B_N * OUT_F;         // (B, OUT, IN)

    float* Wt = (float*)d_ws;                                      // (IN, OUT), 1 MiB

    // Scratch for C: reuse the trace region of d_out (134 MB >= 52 MB needed).
    // trace_gemm runs last and overwrites it. Offset is 8-byte aligned.
    double* C = (double*)trace;

    transposeW<<<256, 256, 0, stream>>>(W, Wt);
    syn_current<<<T_STEPS * B_N, 256, 0, stream>>>(x, Wt, C);
    lif_pointwise<<<B_N * OUT_F / 256, 256, 0, stream>>>(C, S_out, Uh);
    trace_gemm<<<64 * B_N, 256, 0, stream>>>(x, Uh, trace);
}